// Round 8
// baseline (652.848 us; speedup 1.0000x reference)
//
#include <hip/hip_runtime.h>

// ---------------------------------------------------------------------------
// QKGainAttention on MI355X (gfx950), round 8.
// R7 postmortem: no pipe >20% busy; each wave read the full 32KB K/V tile for
// only 16 queries (MFMA:LDS = 1:1), and the all-resident 512-block round had
// a 2x-longest-block tail. R8: 32 queries/wave (two 16-q groups), 128-q
// blocks -- kf/vf LDS reads are query-independent in the S^T formulation, so
// each read now feeds 2 MFMAs (LDS traffic per query halved); grid (16,16,2)
// = exactly 2 blocks/CU with qt-pairing making each CU's tile load constant
// (34); per-group causal guards skip past-diagonal work. Same m=0 softmax,
// dbuf global_load_lds staging, XOR swizzle. ~166 live regs < 256 budget.
// ---------------------------------------------------------------------------

#define DEVINL __device__ __forceinline__

typedef unsigned short u16;
typedef __bf16 bf16x8 __attribute__((ext_vector_type(8)));
typedef float  f32x4  __attribute__((ext_vector_type(4)));
typedef short  short8 __attribute__((ext_vector_type(8)));
typedef u16    u16x4  __attribute__((ext_vector_type(4)));

static constexpr int T_  = 2048;
static constexpr int C_  = 2048;
static constexpr int TC3 = 6144;   // 3*C

DEVINL u16 f2bf(float f) {
  union { float f; unsigned u; } v; v.f = f;
  unsigned r = v.u + 0x7FFFu + ((v.u >> 16) & 1u);   // RNE
  return (u16)(r >> 16);
}
DEVINL float bf2f(u16 s) {
  union { unsigned u; float f; } v; v.u = ((unsigned)s) << 16;
  return v.f;
}
DEVINL bf16x8 ld8(const u16* p) {
  return __builtin_bit_cast(bf16x8, *(const short8*)p);
}
DEVINL f32x4 mfma16(bf16x8 a, bf16x8 b, f32x4 c) {
  return __builtin_amdgcn_mfma_f32_16x16x32_bf16(a, b, c, 0, 0, 0);
}
DEVINL void async_cp16(const u16* gp, u16* lp) {
  __builtin_amdgcn_global_load_lds(
      (const __attribute__((address_space(1))) void*)gp,
      (__attribute__((address_space(3))) void*)lp, 16, 0, 0);
}

// P^T C-frag pair -> B-frag via 3-shuffle quad exchange (verified R3-R7)
DEVINL bf16x8 xform_pb(f32x4 e0, f32x4 e1, int quad) {
  f32x4 Y, Z;
#pragma unroll
  for (int i = 0; i < 4; ++i) {
    Y[i] = (quad & 2) ? e1[i] : e0[i];
    Z[i] = (quad & 2) ? e0[i] : e1[i];
  }
  f32x4 r16, r32, r48;
#pragma unroll
  for (int i = 0; i < 4; ++i) {
    r16[i] = __shfl_xor(Y[i], 16);
    r32[i] = __shfl_xor(Z[i], 32);
    r48[i] = __shfl_xor(Z[i], 48);
  }
  bf16x8 pb;
#pragma unroll
  for (int i = 0; i < 4; ++i) {
    float lo = (quad == 0) ? Y[i] : (quad == 1) ? r48[i] : (quad == 2) ? r32[i] : r16[i];
    float hi = (quad == 0) ? r16[i] : (quad == 1) ? r32[i] : (quad == 2) ? r48[i] : Y[i];
    pb[i]     = (__bf16)lo;
    pb[i + 4] = (__bf16)hi;
  }
  return pb;
}

// ---------------- dtype casts ----------------
__global__ __launch_bounds__(256) void k_cast_x(const float* __restrict__ in,
                                                u16* __restrict__ out) {
  long i = (long)(blockIdx.x * 256 + threadIdx.x) * 4;
  float4 v = *(const float4*)(in + i);
  u16x4 o; o.x = f2bf(v.x); o.y = f2bf(v.y); o.z = f2bf(v.z); o.w = f2bf(v.w);
  *(u16x4*)(out + i) = o;
}
__global__ __launch_bounds__(256) void k_cast_w(const int* __restrict__ in,
                                                u16* __restrict__ out) {
  long i = (long)(blockIdx.x * 256 + threadIdx.x) * 4;
  int4 v = *(const int4*)(in + i);
  u16x4 o; o.x = f2bf((float)v.x); o.y = f2bf((float)v.y);
  o.z = f2bf((float)v.z); o.w = f2bf((float)v.w);
  *(u16x4*)(out + i) = o;
}

// ---------------- GEMM: C[m,n] = (sum_k A[m,k]*Bt[n,k]) * scale[n] ----------
template<bool OUT_BF16>
__global__ __launch_bounds__(256) void k_gemm_bt(
    const u16* __restrict__ A, const u16* __restrict__ Bt,
    const float* __restrict__ scale, void* __restrict__ Cv,
    int N, long K) {
  __shared__ u16 As[128 * 32];
  __shared__ u16 Bs[128 * 32];
  const int tid  = threadIdx.x;
  const int wave = tid >> 6;
  const int lane = tid & 63;
  const int l15  = lane & 15;
  const int quad = lane >> 4;
  const int wm = (wave & 1) * 64;
  const int wn = (wave >> 1) * 64;
  const long bm = (long)blockIdx.y * 128;
  const long bn = (long)blockIdx.x * 128;

  f32x4 acc[4][4] = {};

  const int srow = lane >> 2;
  const int scol = (lane & 3) * 8;

  for (long k0 = 0; k0 < K; k0 += 32) {
#pragma unroll
    for (int i = 0; i < 2; ++i) {
      const int j = wave * 2 + i;
      const int row = j * 16 + srow;
      async_cp16(A  + (bm + row) * K + k0 + scol, &As[j * 512]);
      async_cp16(Bt + (bn + row) * K + k0 + scol, &Bs[j * 512]);
    }
    __syncthreads();
    bf16x8 af[4], bfr[4];
#pragma unroll
    for (int mi = 0; mi < 4; ++mi)
      af[mi] = ld8(&As[(wm + mi * 16 + l15) * 32 + quad * 8]);
#pragma unroll
    for (int ni = 0; ni < 4; ++ni)
      bfr[ni] = ld8(&Bs[(wn + ni * 16 + l15) * 32 + quad * 8]);
#pragma unroll
    for (int mi = 0; mi < 4; ++mi)
#pragma unroll
      for (int ni = 0; ni < 4; ++ni)
        acc[mi][ni] = mfma16(af[mi], bfr[ni], acc[mi][ni]);
    __syncthreads();
  }
#pragma unroll
  for (int ni = 0; ni < 4; ++ni) {
    const long col = bn + wn + ni * 16 + l15;
    const float sc = scale[col];
#pragma unroll
    for (int mi = 0; mi < 4; ++mi) {
      const long row0 = bm + wm + mi * 16 + quad * 4;
#pragma unroll
      for (int r = 0; r < 4; ++r) {
        float v = acc[mi][ni][r] * sc;
        if constexpr (OUT_BF16) ((u16*)Cv)[(row0 + r) * (long)N + col] = f2bf(v);
        else                    ((float*)Cv)[(row0 + r) * (long)N + col] = v;
      }
    }
  }
}

// ---------------- l2norm(q,k); fold qk_gain^2*log2e/sqrt(HD) into q ---------
__global__ __launch_bounds__(256) void k_norm_qk(u16* __restrict__ qkv,
                                                 const float* __restrict__ qk_gain) {
  const int token = blockIdx.x;
  const int wave = threadIdx.x >> 6, lane = threadIdx.x & 63;
  const float g = qk_gain[0];
  const float qmul = g * g * 1.44269504f * 0.08838834764f;
  u16* rowp = qkv + (long)token * TC3;
#pragma unroll
  for (int s = 0; s < 8; ++s) {
    const int seg = wave * 8 + s;
    const int isK = seg >> 4;
    const int h = seg & 15;
    u16* ptr = rowp + isK * C_ + h * 128 + lane * 2;
    unsigned pv = *(const unsigned*)ptr;
    float a = bf2f((u16)(pv & 0xffffu));
    float bb = bf2f((u16)(pv >> 16));
    float ss = a * a + bb * bb;
#pragma unroll
    for (int m = 1; m <= 32; m <<= 1) ss += __shfl_xor(ss, m);
    float denom = fmaxf(sqrtf(ss), 1e-12f);
    float f = (isK ? 1.0f : qmul) / denom;
    u16 o0 = f2bf(a * f), o1 = f2bf(bb * f);
    *(unsigned*)ptr = (unsigned)o0 | ((unsigned)o1 << 16);
  }
}

// ---------------- V transpose: qkv V block -> Vt_g[bz][h][d][t] -------------
__global__ __launch_bounds__(256) void k_vt(const u16* __restrict__ qkv,
                                            u16* __restrict__ vt) {
  const int t0 = blockIdx.x * 64;
  const int h = blockIdx.y, bz = blockIdx.z;
  const int t = threadIdx.x & 63;
  const int d0 = threadIdx.x >> 6;         // 0..3
  const long tokbase = (long)bz * T_;
  const u16* src = qkv + (tokbase + t0 + t) * (long)TC3 + 2 * C_ + h * 128;
  u16* dst = vt + ((long)(bz * 16 + h) * 128) * (long)T_ + t0 + t;
#pragma unroll
  for (int dd = 0; dd < 32; ++dd) {
    const int d = dd * 4 + d0;
    dst[(long)d * T_] = src[d];
  }
}

// ---------------- flash attention: 32 q/wave, m=0 softmax, dbuf staging -----
__global__ __launch_bounds__(256) void k_attn(const u16* __restrict__ qkv,
                                              const u16* __restrict__ vtg,
                                              u16* __restrict__ y) {
  // strip pairing: co-resident blocks (y, y^8) get complementary loads
  const int qt = (blockIdx.y & 8) ? (15 - blockIdx.x) : blockIdx.x;  // 0..15
  const int h  = blockIdx.y;
  const int bz = blockIdx.z;
  const int tid = threadIdx.x, w = tid >> 6, lane = tid & 63;
  const int l15 = lane & 15, quad = lane >> 4;

  __shared__ u16 Ks[2][64 * 128];          // [key][d], XOR-chunk swizzled
  __shared__ u16 Vt[2][128 * 64];          // [d][key], XOR-chunk swizzled

  const long tokbase = (long)bz * T_;
  const int qbase = qt * 128 + w * 32;     // wave's 32 queries
  const int ntiles = 2 * qt + 2;           // 64-key tiles for this block
  const u16* vbase = vtg + ((long)(bz * 16 + h) * 128) * (long)T_;
  const u16* kbase = qkv + tokbase * TC3 + C_ + h * 128;

  // Q fragments for both 16-query groups (B-frag: lane&15=query, quad*8+j=d)
  bf16x8 qf[2][4];
#pragma unroll
  for (int g = 0; g < 2; ++g) {
    const u16* qp = qkv + (tokbase + qbase + g * 16 + l15) * TC3 + h * 128 + quad * 8;
#pragma unroll
    for (int kc = 0; kc < 4; ++kc)
      qf[g][kc] = ld8(qp + kc * 32);
  }

  f32x4 o0[8] = {}, o1[8] = {};            // O^T per group
  float lr0 = 0.f, lr1 = 0.f;              // per-lane partial sums (m == 0)

  auto stage = [&](int ktb, int b) {
#pragma unroll
    for (int j = 0; j < 4; ++j) {
      const int t = w * 4 + j;
      const int p = t * 64 + lane;
      const int r  = p >> 4, ck = p & 15;          // K: row r, chunk ck
      async_cp16(kbase + (long)(ktb + r) * TC3 + ((ck ^ (r & 15)) * 8),
                 &Ks[b][t * 512]);
      const int d  = p >> 3, cv = p & 7;           // V: row d, chunk cv
      async_cp16(vbase + (long)d * T_ + ktb + ((cv ^ (d & 7)) * 8),
                 &Vt[b][t * 512]);
    }
  };

  stage(0, 0);
  __syncthreads();                         // drain tile-0 staging
  int b = 0;

  for (int kt = 0; kt < ntiles; ++kt) {
    const int ktb = kt * 64;
    if (kt + 1 < ntiles) stage(ktb + 64, b ^ 1);

    const bool ga1 = (ktb <= qbase + 31);  // group 1 (and wave) active
    const bool ga0 = (ktb <= qbase + 15);  // group 0 active
    if (ga1) {
      // --- S^T = K·Q^T: kf shared across groups (2 MFMAs per LDS read) ---
      f32x4 s0[4], s1[4];
#pragma unroll
      for (int kb = 0; kb < 4; ++kb) {
        f32x4 a0 = {0.f, 0.f, 0.f, 0.f}, a1 = {0.f, 0.f, 0.f, 0.f};
#pragma unroll
        for (int kc = 0; kc < 4; ++kc) {
          bf16x8 kf = ld8(&Ks[b][(kb * 16 + l15) * 128 + (((kc * 4 + quad) ^ l15) * 8)]);
          if (ga0) a0 = mfma16(kf, qf[0][kc], a0);
          a1 = mfma16(kf, qf[1][kc], a1);
        }
        const int keyb = ktb + kb * 16 + quad * 4;
        if (ga0 && ktb + 63 > qbase) {
#pragma unroll
          for (int r = 0; r < 4; ++r)
            if (keyb + r > qbase + l15) a0[r] = -1e30f;
        }
        if (ktb + 63 > qbase + 16) {
#pragma unroll
          for (int r = 0; r < 4; ++r)
            if (keyb + r > qbase + 16 + l15) a1[r] = -1e30f;
        }
        s0[kb] = a0; s1[kb] = a1;
      }
      // --- m=0 softmax: P = exp2(s) (|s| bounded); per-lane partial l ---
#pragma unroll
      for (int kb = 0; kb < 4; ++kb)
#pragma unroll
        for (int r = 0; r < 4; ++r) {
          if (ga0) {
            float p0 = __builtin_amdgcn_exp2f(s0[kb][r]);
            s0[kb][r] = p0;
            lr0 += p0;
          }
          float p1 = __builtin_amdgcn_exp2f(s1[kb][r]);
          s1[kb][r] = p1;
          lr1 += p1;
        }
      // --- O^T += V^T P^T: vf shared across groups ---
#pragma unroll
      for (int kc2 = 0; kc2 < 2; ++kc2) {
        bf16x8 pb0, pb1;
        if (ga0) pb0 = xform_pb(s0[kc2 * 2], s0[kc2 * 2 + 1], quad);
        pb1 = xform_pb(s1[kc2 * 2], s1[kc2 * 2 + 1], quad);
#pragma unroll
        for (int db = 0; db < 8; ++db) {
          bf16x8 vf = ld8(&Vt[b][(db * 16 + l15) * 64 + (((kc2 * 4 + quad) ^ (l15 & 7)) * 8)]);
          if (ga0) o0[db] = mfma16(vf, pb0, o0[db]);
          o1[db] = mfma16(vf, pb1, o1[db]);
        }
      }
    }
    if (kt + 1 < ntiles) __syncthreads();  // drains prefetch + guards buffers
    b ^= 1;
  }
  // --- epilogue: reduce l across quads (2 shuffles/group), write O^T ---
  lr0 += __shfl_xor(lr0, 16); lr0 += __shfl_xor(lr0, 32);
  lr1 += __shfl_xor(lr1, 16); lr1 += __shfl_xor(lr1, 32);
  const float il0 = 1.0f / lr0, il1 = 1.0f / lr1;
  u16* yp0 = y + (tokbase + qbase + l15) * (long)C_ + h * 128 + quad * 4;
  u16* yp1 = yp0 + 16 * (long)C_;
#pragma unroll
  for (int db = 0; db < 8; ++db) {
    u16x4 p0, p1;
#pragma unroll
    for (int r = 0; r < 4; ++r) {
      p0[r] = f2bf(o0[db][r] * il0);
      p1[r] = f2bf(o1[db][r] * il1);
    }
    *(u16x4*)(yp0 + db * 16) = p0;
    *(u16x4*)(yp1 + db * 16) = p1;
  }
}

// ---------------------------------------------------------------------------
extern "C" void kernel_launch(void* const* d_in, const int* in_sizes, int n_in,
                              void* d_out, int out_size, void* d_ws, size_t ws_size,
                              hipStream_t stream) {
  const float* x    = (const float*)d_in[0];
  const int*   aw   = (const int*)d_in[1];
  const float* asc  = (const float*)d_in[2];
  const int*   pw   = (const int*)d_in[3];
  const float* psc  = (const float*)d_in[4];
  const float* gain = (const float*)d_in[5];

  char* ws = (char*)d_ws;
  u16* xb  = (u16*)(ws);                         // 16.78 MB (reused as Vt_g)
  u16* wab = (u16*)(ws + 16777216UL);
  u16* wpb = (u16*)(ws + 41943040UL);
  u16* qkv = (u16*)(ws + 50331648UL);
  u16* yb  = (u16*)(ws + 100663296UL);
  u16* vtg = xb;                                 // x_bf16 dead after QKV GEMM

  k_cast_x<<<8192, 256, 0, stream>>>(x, xb);
  k_cast_w<<<12288, 256, 0, stream>>>(aw, wab);
  k_cast_w<<<4096, 256, 0, stream>>>(pw, wpb);
  k_gemm_bt<true><<<dim3(48, 32), 256, 0, stream>>>(xb, wab, asc, qkv, TC3, (long)C_);
  k_norm_qk<<<4096, 256, 0, stream>>>(qkv, gain);
  k_vt<<<dim3(32, 16, 2), 256, 0, stream>>>(qkv, vtg);
  k_attn<<<dim3(16, 16, 2), 256, 0, stream>>>(qkv, vtg, yb);
  k_gemm_bt<false><<<dim3(16, 32), 256, 0, stream>>>(yb, wpb, psc, (float*)d_out, C_, (long)C_);
}